// Round 13
// baseline (267.365 us; speedup 1.0000x reference)
//
#include <hip/hip_runtime.h>
#include <math.h>

// RelativeAttention: out = round((x_n @ a_n^T)/0.05)*0.05 @ values
//
// Round 30 (from r29 WIN @ 264.0us): b-row-bucketed fixup.
// r29's budget decomposition: prep 17 + gemm1 190 (incl ~78us fused fixup)
// + gemm2 57. Fixup is L3-BW-bound (~1.07GB @ 13.7TB/s): each flag re-read
// 8KB of x+anc rows. Flags share x-rows (~8 flags per b-row) -> bucket BY b:
//  - gemm1 epilogue scatters flags to counts_b[16384]/lists_b[16384][32]
//    (u16 anchor idx; 8 flags share one 64B line). Overflow (P~2e-11/row)
//    -> spill list, drained by a dedicated block with the old per-flag path.
//  - fixupb_k: one wave per b-row; x-row loaded ONCE into 16 VGPRs; per
//    flag only the anc row (8MB, L2-resident) is read, 2-deep pipelined.
//    x-traffic 550MB -> 64MB.
//  - f64 dot tree / reduce / hedge IDENTICAL to r24-r29 -> kb2 bit-identical
//    (absmax canary 2.685547e-3). GEMM cores byte-identical to r29.
//
// ws layout (bytes):
//   [0x0,       0x24000)   inv_norms f64 (16384 x | 2048 anchors)
//   [0x24000,   0x34000)   counts_b u32[16384]
//   [0x34000,   0x134000)  lists_b u16[16384][32]
//   [0x134000,  0x138004)  ovf u32[1+4096]
//   [0x324000,  0x2324000) xh f16 [16384][1024] (32MB)
//   [0x2324000, 0x2724000) ah f16 [2048][1024] (4MB)
//   [0x2724000, 0x2B24000) vbT bf16 [1024][2048] (values^T, 4MB)
//   [0x2B24000, 0x6B24000) kb2 bf16 [16384][2048] (2*bin, odd = midpoint)

#define B_ROWS 16384
#define A_ROWS 2048
#define D_DIM  1024
#define H_DIM  1024
#define BCAP 32u
#define OCAP 4096u

typedef __attribute__((ext_vector_type(8))) short short8;
typedef __attribute__((ext_vector_type(8))) _Float16 half8;
typedef __attribute__((ext_vector_type(4))) float f32x4;

__device__ inline unsigned short bf16_rne(float f) {
  unsigned int u = __float_as_uint(f);
  unsigned int r = (u + 0x7FFFu + ((u >> 16) & 1u)) >> 16;
  return (unsigned short)r;
}
__device__ inline unsigned short f16_bits(float f) {
  _Float16 h = (_Float16)f;
  return __builtin_bit_cast(unsigned short, h);
}
__device__ inline void gload16(const void* g, void* l) {
  __builtin_amdgcn_global_load_lds(
      (const __attribute__((address_space(1))) unsigned int*)g,
      (__attribute__((address_space(3))) unsigned int*)l, 16, 0, 0);
}

template <bool F16>
__device__ __forceinline__ f32x4 mm16(short8 a, short8 b, f32x4 c) {
  if constexpr (F16)
    return __builtin_amdgcn_mfma_f32_16x16x32_f16(
        __builtin_bit_cast(half8, a), __builtin_bit_cast(half8, b), c, 0, 0, 0);
  else
    return __builtin_amdgcn_mfma_f32_16x16x32_bf16(a, b, c, 0, 0, 0);
}

// f64 dot helper: IDENTICAL summation tree to r24-r29 fixup.
__device__ __forceinline__ double dot16(const float4 xc0, const float4 xc1,
                                        const float4 xc2, const float4 xc3,
                                        const float4 ac0, const float4 ac1,
                                        const float4 ac2, const float4 ac3) {
  double p0 = (double)xc0.x * (double)ac0.x + (double)xc0.y * (double)ac0.y +
              (double)xc0.z * (double)ac0.z + (double)xc0.w * (double)ac0.w;
  double p1 = (double)xc1.x * (double)ac1.x + (double)xc1.y * (double)ac1.y +
              (double)xc1.z * (double)ac1.z + (double)xc1.w * (double)ac1.w;
  double p2 = (double)xc2.x * (double)ac2.x + (double)xc2.y * (double)ac2.y +
              (double)xc2.z * (double)ac2.z + (double)xc2.w * (double)ac2.w;
  double p3 = (double)xc3.x * (double)ac3.x + (double)xc3.y * (double)ac3.y +
              (double)xc3.z * (double)ac3.z + (double)xc3.w * (double)ac3.w;
  double s = (p0 + p1) + (p2 + p3);
  s += __shfl_xor(s, 32);
  s += __shfl_xor(s, 16);
  s += __shfl_xor(s, 8);
  s += __shfl_xor(s, 4);
  s += __shfl_xor(s, 2);
  s += __shfl_xor(s, 1);
  return s;
}
__device__ __forceinline__ void fixwrite(double s, int b, int a,
                                         const double* __restrict__ inv_norms,
                                         unsigned short* __restrict__ kb2) {
  const double sim = s * inv_norms[b] * inv_norms[B_ROWS + a];
  const double kr = sim / 0.05;
  const double r = rint(kr);
  const double fr = kr - r;
  int k2 = 2 * (int)r;
  if (0.5 - fabs(fr) < 2.5e-6) k2 += (fr > 0.0) ? 1 : -1;  // midpoint hedge
  kb2[(size_t)b * A_ROWS + a] = bf16_rne((float)k2);       // exact int
}

// ---- merged prep: norm+f16 (x|anchor rows) + values^T + zero cnts/ovf -----
__global__ __launch_bounds__(256) void prep_k(
    const float* __restrict__ x, const float* __restrict__ anc,
    const float* __restrict__ values, double* __restrict__ inv_norms,
    unsigned short* __restrict__ xh, unsigned short* __restrict__ ah,
    unsigned short* __restrict__ vbT, unsigned int* __restrict__ counts_b,
    unsigned int* __restrict__ ovf) {
  const int blk = blockIdx.x;
  const int t = threadIdx.x;
  if (blk < B_ROWS + A_ROWS) {
    // ---- normprep branch (r3-proven f64 tree, fp-contract off) ----
#pragma clang fp contract(off)
    const bool isx = blk < B_ROWS;
    const int r = isx ? blk : blk - B_ROWS;
    if (isx && t == 0) counts_b[r] = 0;
    const float* src = isx ? x + (size_t)r * D_DIM : anc + (size_t)r * D_DIM;
    double* inv_out = isx ? inv_norms + r : inv_norms + B_ROWS + r;
    unsigned short* dst = isx ? xh + (size_t)r * D_DIM : ah + (size_t)r * D_DIM;
    const float4 v = reinterpret_cast<const float4*>(src)[t];
    double s = (double)v.x * (double)v.x + (double)v.y * (double)v.y +
               (double)v.z * (double)v.z + (double)v.w * (double)v.w;
#pragma unroll
    for (int off = 32; off > 0; off >>= 1) s += __shfl_down(s, off);
    __shared__ double red[4];
    __shared__ double sinv;
    if ((t & 63) == 0) red[t >> 6] = s;
    __syncthreads();
    if (t == 0) {
      const double n = sqrt(red[0] + red[1] + red[2] + red[3]);
      const double inv = 1.0 / fmax(n, 1e-12);
      *inv_out = inv;
      sinv = inv;
    }
    __syncthreads();
    const float invn = (float)sinv;
    ushort4 o;
    o.x = f16_bits(v.x * invn); o.y = f16_bits(v.y * invn);
    o.z = f16_bits(v.z * invn); o.w = f16_bits(v.w * invn);
    reinterpret_cast<ushort4*>(dst)[t] = o;
  } else {
    // ---- prep_vt branch: 16x16 transpose tile (+ zero ovf, tile 0) ----
    const int tile = blk - (B_ROWS + A_ROWS);
    const int tx = t & 15, ty = t >> 4;
    __shared__ float sm[16][17];
    if (tile == 0 && t == 0) ovf[0] = 0;
    const int h0 = (tile & 63) * 16, a0 = (tile >> 6) * 16;
    sm[ty][tx] = values[(size_t)(a0 + ty) * H_DIM + h0 + tx];
    __syncthreads();
    vbT[(size_t)(h0 + ty) * A_ROWS + a0 + tx] = bf16_rne(sm[tx][ty]);
  }
}

// ------ 256x256 / BK=64 / 8-wave / 8-phase read-ahead GEMM core -----------
// LDS: buf0 {A:[256][64] @0, B @16384}, buf1 {A @32768, B @49152} (shorts).
// Chunk-XOR swizzle: row r's chunk k (16B) lives at slot k^(r&7); staging
// pre-swizzles the per-lane GLOBAL source so the LDS dest stays linear.
#define GBAR() do { __builtin_amdgcn_s_barrier(); \
                    asm volatile("" ::: "memory"); } while (0)
#define GVMC(n) asm volatile("s_waitcnt vmcnt(" #n ")" ::: "memory")

#define SCA(buf, c, kv) gload16(aS + (size_t)(c) * 64 * KDIM + (kv), \
                                (buf) + (c) * 4096 + tid * 8)
#define SCB(buf, c, kv) gload16(bS + (size_t)(c) * 64 * KDIM + (kv), \
                                (buf) + (c) * 4096 + tid * 8)

// frag reads: plain C++ short8 loads off precomputed swizzled bases;
// compiler inserts counted lgkmcnt and interleaves with MFMA.
#define LDX(pk0, pk1, mh) do { \
    _Pragma("unroll") for (int m_ = 0; m_ < 4; ++m_) { \
      Xf[0][m_] = *reinterpret_cast<const short8*>((pk0) + (mh) * 8192 + m_ * 1024); \
      Xf[1][m_] = *reinterpret_cast<const short8*>((pk1) + (mh) * 8192 + m_ * 1024); \
    } } while (0)

#define LDB(pk0, pk1, nh) do { \
    _Pragma("unroll") for (int n_ = 0; n_ < 2; ++n_) { \
      Bf[nh][0][n_] = *reinterpret_cast<const short8*>((pk0) + (nh) * 8192 + n_ * 1024); \
      Bf[nh][1][n_] = *reinterpret_cast<const short8*>((pk1) + (nh) * 8192 + n_ * 1024); \
    } } while (0)

#define MM4(mh, nh) do { \
    __builtin_amdgcn_s_setprio(1); \
    _Pragma("unroll") for (int ki_ = 0; ki_ < 2; ++ki_) \
    _Pragma("unroll") for (int m_ = 0; m_ < 4; ++m_) \
    _Pragma("unroll") for (int n_ = 0; n_ < 2; ++n_) \
      acc[(mh) * 4 + m_][(nh) * 2 + n_] = mm16<F16>( \
          Xf[ki_][m_], Bf[nh][ki_][n_], acc[(mh) * 4 + m_][(nh) * 2 + n_]); \
    __builtin_amdgcn_s_setprio(0); \
  } while (0)

template <int KDIM, bool F16>
__device__ __forceinline__ void gemm_core(
    const unsigned short* __restrict__ Amat, int m0,
    const unsigned short* __restrict__ Bmat, int n0,
    unsigned short* smem, f32x4 (&acc)[8][4], const int tid) {
  static_assert(KDIM % 128 == 0 && KDIM >= 256, "KDIM");
  const int lane = tid & 63, w = tid >> 6;
  const int wr = w >> 2, wc = w & 3;
  const int cl = lane & 15, kg = lane >> 4;
  unsigned short* const A0b = smem;
  unsigned short* const B0b = smem + 16384;
  unsigned short* const A1b = smem + 32768;
  unsigned short* const B1b = smem + 49152;
  // staging geometry: call c covers rows c*64 + (tid>>3), chunk slot tid&7;
  // source chunk = slot ^ (row&7); (c*64)&7==0 so the XOR is c-invariant.
  const int srow = tid >> 3;
  const int tcs = (tid & 7) ^ (srow & 7);
  const unsigned short* aS = Amat + (size_t)(m0 + srow) * KDIM + tcs * 8;
  const unsigned short* bS = Bmat + (size_t)(n0 + srow) * KDIM + tcs * 8;

  // frag-read swizzle constants: row&7 == cl&7 for all frag rows, so the
  // chunk index is lane-constant: cc = (ki*4+kg)^(cl&7); ki flips ^32 shorts.
  const int cc0 = kg ^ (cl & 7);
  const int oA0 = (wr * 64 + cl) * 64 + cc0 * 8;
  const int oA1 = oA0 ^ 32;
  const int oB0 = (wc * 32 + cl) * 64 + cc0 * 8;
  const int oB1 = oB0 ^ 32;
  const unsigned short* const pA0k0 = A0b + oA0;
  const unsigned short* const pA0k1 = A0b + oA1;
  const unsigned short* const pA1k0 = A1b + oA0;
  const unsigned short* const pA1k1 = A1b + oA1;
  const unsigned short* const pB0k0 = B0b + oB0;
  const unsigned short* const pB0k1 = B0b + oB1;
  const unsigned short* const pB1k0 = B1b + oB0;
  const unsigned short* const pB1k1 = B1b + oB1;

  short8 Xf[2][4], Bf[2][2][2];

  // prologue: t0 full (8) + t1 sans A-h1 (6) = 14 loads; wait all but t1's 6
  SCA(A0b, 0, 0); SCA(A0b, 1, 0);
  SCB(B0b, 0, 0); SCB(B0b, 1, 0);
  SCB(B0b, 2, 0); SCB(B0b, 3, 0);
  SCA(A0b, 2, 0); SCA(A0b, 3, 0);
  SCA(A1b, 0, 64); SCA(A1b, 1, 64);
  SCB(B1b, 0, 64); SCB(B1b, 1, 64);
  SCB(B1b, 2, 64); SCB(B1b, 3, 64);
  GVMC(6);
  GBAR();
  LDX(pA0k0, pA0k1, 0);  // X0(t0)
  LDB(pB0k0, pB0k1, 0);  // B0(t0)

  constexpr int G = KDIM / 128;  // groups of 2 K-tiles
#pragma unroll 1
  for (int g = 0; g < G - 1; ++g) {
    const int kA = g * 128 + 64;   // t1 = 2g+1 (buf1): A-h1 staged ph1
    const int kB = g * 128 + 128;  // t2 = 2g+2 (buf0): staged ph2-5
    const int kC = g * 128 + 192;  // t3 = 2g+3 (buf1): 3 halves, ph6-8
    // ph1: MM(0,0)=X0*B0; read B1 (for ph2)
    SCA(A1b, 2, kA); SCA(A1b, 3, kA);
    LDB(pB0k0, pB0k1, 1);
    MM4(0, 0);
    GBAR();
    // ph2: MM(0,1)=X0*B1; post-MM read X1 (SSA: MM reads old Xf)
    SCA(A0b, 0, kB); SCA(A0b, 1, kB);
    MM4(0, 1);
    LDX(pA0k0, pA0k1, 1);
    GBAR();
    // ph3: MM(1,0)=X1*B0
    SCB(B0b, 0, kB); SCB(B0b, 1, kB);
    MM4(1, 0);
    GBAR();
    // ph4: MM(1,1)=X1*B1 first; then vmc6+BAR (t1 resident all-waves);
    // then read X0',B0' (drain under ph5's MM issue).
    SCB(B0b, 2, kB); SCB(B0b, 3, kB);
    MM4(1, 1);
    GVMC(6);
    GBAR();
    LDX(pA1k0, pA1k1, 0);
    LDB(pB1k0, pB1k1, 0);
    GBAR();
    // ph5: MM(0,0)'=X0'*B0'; read B1'
    SCA(A0b, 2, kB); SCA(A0b, 3, kB);
    LDB(pB1k0, pB1k1, 1);
    MM4(0, 0);
    GBAR();
    // ph6: MM(0,1)'=X0'*B1'; post-MM read X1'
    SCA(A1b, 0, kC); SCA(A1b, 1, kC);
    MM4(0, 1);
    LDX(pA1k0, pA1k1, 1);
    GBAR();
    // ph7: MM(1,0)'=X1'*B0'
    SCB(B1b, 0, kC); SCB(B1b, 1, kC);
    MM4(1, 0);
    GBAR();
    // ph8: MM(1,1)'=X1'*B1' first; vmc6+BAR (t2 resident); read X0'',B0''
    SCB(B1b, 2, kC); SCB(B1b, 3, kC);
    MM4(1, 1);
    GVMC(6);
    GBAR();
    LDX(pA0k0, pA0k1, 0);
    LDB(pB0k0, pB0k1, 0);
    GBAR();
  }
  // tail group: t_{2G-2}(buf0), t_{2G-1}(buf1); only t_{2G-1} A-h1 to stage
  {
    const int kA = KDIM - 64;
    SCA(A1b, 2, kA); SCA(A1b, 3, kA);
    LDB(pB0k0, pB0k1, 1);
    MM4(0, 0);
    GBAR();
    MM4(0, 1);
    LDX(pA0k0, pA0k1, 1);
    GBAR();
    MM4(1, 0);
    GBAR();
    MM4(1, 1);
    GVMC(0);
    GBAR();
    LDX(pA1k0, pA1k1, 0);
    LDB(pB1k0, pB1k1, 0);
    GBAR();
    LDB(pB1k0, pB1k1, 1);
    MM4(0, 0);
    GBAR();
    MM4(0, 1);
    LDX(pA1k0, pA1k1, 1);
    GBAR();
    MM4(1, 0);
    GBAR();
    MM4(1, 1);
  }
}

// ---- GEMM1: f16 core + quantize + b-bucketed flag scatter + flush ---------
__global__ __launch_bounds__(512, 2) void gemm1_k(
    const unsigned short* __restrict__ xh, const unsigned short* __restrict__ ah,
    unsigned short* __restrict__ kb2, unsigned int* __restrict__ counts_b,
    unsigned short* __restrict__ lists_b, unsigned int* __restrict__ ovf) {
  __shared__ __align__(128) unsigned short smem[65536];  // 128 KB

  const int tid = threadIdx.x, lane = tid & 63, w = tid >> 6;
  const int wr = w >> 2, wc = w & 3;
  const int cl = lane & 15, kg = lane >> 4;
  // XCD-bijective swizzle (m204; nwg=512, nwg%8==0, q=64)
  const int orig = blockIdx.y * 8 + blockIdx.x;
  const int swz = (orig & 7) * 64 + (orig >> 3);
  const int m0 = (swz >> 3) * 256, n0 = (swz & 7) * 256;

  f32x4 acc[8][4];
#pragma unroll
  for (int m = 0; m < 8; ++m)
#pragma unroll
    for (int n = 0; n < 4; ++n)
#pragma unroll
      for (int q = 0; q < 4; ++q) acc[m][n][q] = 0.0f;

  gemm_core<D_DIM, true>(xh, m0, ah, n0, smem, acc, tid);

  // ---- epilogue: quantize -> bf16 2k in LDS (XOR-swz) + b-bucket flags ---
  __syncthreads();
  unsigned short* sq = smem;  // [256][256] bf16, chunk-swizzled
#pragma unroll
  for (int mi = 0; mi < 8; ++mi)
#pragma unroll
    for (int ni = 0; ni < 4; ++ni) {
      const int rowb = (mi >> 2) * 128 + wr * 64 + (mi & 3) * 16 + kg * 4;
      const int col = (ni >> 1) * 128 + wc * 32 + (ni & 1) * 16 + cl;
#pragma unroll
      for (int reg = 0; reg < 4; ++reg) {
        const int row = rowb + reg;
        const float kr = acc[mi][ni][reg] * 20.0f;
        const float rr = rintf(kr);
        if (0.5f - fabsf(kr - rr) < 2e-3f) {  // r7-r29-validated window
          const int gb = m0 + row, ga = n0 + col;
          const unsigned int li = atomicAdd(&counts_b[gb], 1u);
          if (li < BCAP) lists_b[(size_t)gb * BCAP + li] = (unsigned short)ga;
          else {
            const unsigned int oi = atomicAdd(&ovf[0], 1u);
            if (oi < OCAP) ovf[1 + oi] = ((unsigned int)gb << 11) | (unsigned int)ga;
          }
        }
        // swizzled store: chunk (col>>3) with low 3 bits XOR (row&7)
        const int ch = col >> 3;
        const int csw = (ch & 24) | ((ch & 7) ^ (row & 7));
        sq[row * 256 + csw * 8 + (col & 7)] =
            bf16_rne((float)(2 * (int)rr));  // exact
      }
    }
  __syncthreads();
  {
    const int row = tid >> 1, half = tid & 1;
    unsigned short* dst = kb2 + (size_t)(m0 + row) * A_ROWS + n0 + half * 128;
#pragma unroll
    for (int j = 0; j < 16; ++j) {
      const int creal = half * 16 + j;
      const int csw = (creal & 24) | ((creal & 7) ^ (row & 7));
      reinterpret_cast<int4*>(dst)[j] =
          *reinterpret_cast<const int4*>(sq + row * 256 + csw * 8);
    }
  }
}

// ---- fixup: one wave per b-row; x-row in regs, per-flag anc read (L2) -----
__global__ __launch_bounds__(256) void fixupb_k(
    const float* __restrict__ x, const float* __restrict__ anc,
    const double* __restrict__ inv_norms, const unsigned int* __restrict__ counts_b,
    const unsigned short* __restrict__ lists_b, const unsigned int* __restrict__ ovf,
    unsigned short* __restrict__ kb2) {
  const int lane = threadIdx.x & 63, wib = threadIdx.x >> 6;
  if (blockIdx.x < B_ROWS / 4) {
    const int b = blockIdx.x * 4 + wib;
    unsigned int cnt = counts_b[b];
    if (cnt > BCAP) cnt = BCAP;
    if (cnt == 0) return;
    const float4* xp = reinterpret_cast<const float4*>(x + (size_t)b * D_DIM) + lane;
    const float4 x0 = xp[0], x1 = xp[64], x2 = xp[128], x3 = xp[192];
    const unsigned short* lst = lists_b + (size_t)b * BCAP;
    int a = lst[0];
    const float4* ap = reinterpret_cast<const float4*>(anc + (size_t)a * D_DIM) + lane;
    float4 a0 = ap[0], a1 = ap[64], a2 = ap[128], a3 = ap[192];
    for (unsigned int i = 0;;) {
      const unsigned int inext = i + 1;
      const bool have = inext < cnt;
      int an = 0;
      float4 n0, n1, n2, n3;
      if (have) {  // prefetch next anc row (hides under current compute)
        an = lst[inext];
        const float4* np = reinterpret_cast<const float4*>(anc + (size_t)an * D_DIM) + lane;
        n0 = np[0]; n1 = np[64]; n2 = np[128]; n3 = np[192];
      }
      const double s = dot16(x0, x1, x2, x3, a0, a1, a2, a3);
      if (lane == 0) fixwrite(s, b, a, inv_norms, kb2);
      if (!have) break;
      i = inext; a = an;
      a0 = n0; a1 = n1; a2 = n2; a3 = n3;
    }
  } else {
    // overflow drain (expected empty; correctness fallback)
    unsigned int oc = ovf[0];
    if (oc > OCAP) oc = OCAP;
    for (unsigned int i = (unsigned int)wib; i < oc; i += 4) {
      const unsigned int code = ovf[1 + i];
      const int b = (int)(code >> 11), a = (int)(code & 2047u);
      const float4* xp = reinterpret_cast<const float4*>(x + (size_t)b * D_DIM) + lane;
      const float4* ap = reinterpret_cast<const float4*>(anc + (size_t)a * D_DIM) + lane;
      const double s = dot16(xp[0], xp[64], xp[128], xp[192],
                             ap[0], ap[64], ap[128], ap[192]);
      if (lane == 0) fixwrite(s, b, a, inv_norms, kb2);
    }
  }
}

// ---- GEMM2: bf16 chain, K=2048, 256^2 8-phase core, out = .025*k2@vbT -----
__global__ __launch_bounds__(512, 2) void gemm2_k(
    const unsigned short* __restrict__ kb2, const unsigned short* __restrict__ vbT,
    float* __restrict__ out) {
  __shared__ __align__(128) unsigned short smem[65536];  // 128 KB

  const int tid = threadIdx.x, lane = tid & 63, w = tid >> 6;
  const int wr = w >> 2, wc = w & 3;
  const int cl = lane & 15, kg = lane >> 4;
  // XCD-bijective swizzle (nwg=256, q=32)
  const int orig = blockIdx.y * 4 + blockIdx.x;
  const int swz = (orig & 7) * 32 + (orig >> 3);
  const int m0 = (swz >> 2) * 256, h0 = (swz & 3) * 256;

  f32x4 acc[8][4];
#pragma unroll
  for (int m = 0; m < 8; ++m)
#pragma unroll
    for (int n = 0; n < 4; ++n)
#pragma unroll
      for (int q = 0; q < 4; ++q) acc[m][n][q] = 0.0f;

  gemm_core<A_ROWS, false>(kb2, m0, vbT, h0, smem, acc, tid);

#pragma unroll
  for (int mi = 0; mi < 8; ++mi)
#pragma unroll
    for (int ni = 0; ni < 4; ++ni) {
      const int rowb = (mi >> 2) * 128 + wr * 64 + (mi & 3) * 16 + kg * 4;
      const int col = (ni >> 1) * 128 + wc * 32 + (ni & 1) * 16 + cl;
#pragma unroll
      for (int reg = 0; reg < 4; ++reg)
        out[(size_t)(m0 + rowb + reg) * H_DIM + h0 + col] =
            0.025f * acc[mi][ni][reg];
    }
}

// ---------------------------------------------------------------------------
extern "C" void kernel_launch(void* const* d_in, const int* in_sizes, int n_in,
                              void* d_out, int out_size, void* d_ws, size_t ws_size,
                              hipStream_t stream) {
  const float* x      = (const float*)d_in[0];
  const float* anc    = (const float*)d_in[1];
  const float* values = (const float*)d_in[2];
  float* out = (float*)d_out;

  char* ws = (char*)d_ws;
  double* inv_norms       = (double*)(ws);
  unsigned int* counts_b  = (unsigned int*)(ws + 0x24000);
  unsigned short* lists_b = (unsigned short*)(ws + 0x34000);
  unsigned int* ovf       = (unsigned int*)(ws + 0x134000);
  unsigned short* xh      = (unsigned short*)(ws + 0x324000);
  unsigned short* ah      = (unsigned short*)(ws + 0x2324000);
  unsigned short* vbT     = (unsigned short*)(ws + 0x2724000);
  unsigned short* kb2     = (unsigned short*)(ws + 0x2B24000);

  prep_k<<<B_ROWS + A_ROWS + (H_DIM / 16) * (A_ROWS / 16), 256, 0, stream>>>(
      x, anc, values, inv_norms, xh, ah, vbT, counts_b, ovf);
  gemm1_k<<<dim3(A_ROWS / 256, B_ROWS / 256), 512, 0, stream>>>(
      xh, ah, kb2, counts_b, lists_b, ovf);
  fixupb_k<<<B_ROWS / 4 + 1, 256, 0, stream>>>(
      x, anc, inv_norms, counts_b, lists_b, ovf, kb2);
  gemm2_k<<<dim3(H_DIM / 256, B_ROWS / 256), 512, 0, stream>>>(kb2, vbT, out);
}

// Round 14
// 263.023 us; speedup vs baseline: 1.0165x; 1.0165x over previous
//
#include <hip/hip_runtime.h>
#include <math.h>

// RelativeAttention: out = round((x_n @ a_n^T)/0.05)*0.05 @ values
//
// Round 31: REVERT to r29 (best, 264.0us). r30's b-bucketed fixup was a
// wash: budget decomposition (prep 18 + gemm1 111.5 + fixpath + gemm2 ~105
// + gaps) shows r29-fused fixpath ~29us == r30's scatter(10)+fixupb(19),
// but r30 pays +3.4us in global atomics/gaps. Fused-in-gemm1 fixup (LDS
// flag list, 8 waves, 2-deep pipelined gather, f64 dot identical to
// r24-r30 -> bit-identical kb2) is the better structure.
//  - GEMM cores: r24 single-barrier read-ahead 8-phase (six schedule
//    variants 110-120us -> family closed; 32x32 = bank-conflict regression).
//  - prep: merged normprep_x/a + vt transpose (BW-saturated ~6.4TB/s).
//  - absmax canary 2.685547e-3.
//
// ws layout (bytes):
//   [0x0,       0x24000)   inv_norms f64 (16384 x | 2048 anchors)
//   [0x324000,  0x2324000) xh f16 [16384][1024] (32MB)
//   [0x2324000, 0x2724000) ah f16 [2048][1024] (4MB)
//   [0x2724000, 0x2B24000) vbT bf16 [1024][2048] (values^T, 4MB)
//   [0x2B24000, 0x6B24000) kb2 bf16 [16384][2048] (2*bin, odd = midpoint)

#define B_ROWS 16384
#define A_ROWS 2048
#define D_DIM  1024
#define H_DIM  1024
#define LCAP 2040u

typedef __attribute__((ext_vector_type(8))) short short8;
typedef __attribute__((ext_vector_type(8))) _Float16 half8;
typedef __attribute__((ext_vector_type(4))) float f32x4;

__device__ inline unsigned short bf16_rne(float f) {
  unsigned int u = __float_as_uint(f);
  unsigned int r = (u + 0x7FFFu + ((u >> 16) & 1u)) >> 16;
  return (unsigned short)r;
}
__device__ inline unsigned short f16_bits(float f) {
  _Float16 h = (_Float16)f;
  return __builtin_bit_cast(unsigned short, h);
}
__device__ inline void gload16(const void* g, void* l) {
  __builtin_amdgcn_global_load_lds(
      (const __attribute__((address_space(1))) unsigned int*)g,
      (__attribute__((address_space(3))) unsigned int*)l, 16, 0, 0);
}

template <bool F16>
__device__ __forceinline__ f32x4 mm16(short8 a, short8 b, f32x4 c) {
  if constexpr (F16)
    return __builtin_amdgcn_mfma_f32_16x16x32_f16(
        __builtin_bit_cast(half8, a), __builtin_bit_cast(half8, b), c, 0, 0, 0);
  else
    return __builtin_amdgcn_mfma_f32_16x16x32_bf16(a, b, c, 0, 0, 0);
}

// ---- merged prep: norm+f16 (x rows | anchor rows) + values^T --------------
__global__ __launch_bounds__(256) void prep_k(
    const float* __restrict__ x, const float* __restrict__ anc,
    const float* __restrict__ values, double* __restrict__ inv_norms,
    unsigned short* __restrict__ xh, unsigned short* __restrict__ ah,
    unsigned short* __restrict__ vbT) {
  const int blk = blockIdx.x;
  const int t = threadIdx.x;
  if (blk < B_ROWS + A_ROWS) {
    // ---- normprep branch (r3-proven f64 tree, fp-contract off) ----
#pragma clang fp contract(off)
    const bool isx = blk < B_ROWS;
    const int r = isx ? blk : blk - B_ROWS;
    const float* src = isx ? x + (size_t)r * D_DIM : anc + (size_t)r * D_DIM;
    double* inv_out = isx ? inv_norms + r : inv_norms + B_ROWS + r;
    unsigned short* dst = isx ? xh + (size_t)r * D_DIM : ah + (size_t)r * D_DIM;
    const float4 v = reinterpret_cast<const float4*>(src)[t];
    double s = (double)v.x * (double)v.x + (double)v.y * (double)v.y +
               (double)v.z * (double)v.z + (double)v.w * (double)v.w;
#pragma unroll
    for (int off = 32; off > 0; off >>= 1) s += __shfl_down(s, off);
    __shared__ double red[4];
    __shared__ double sinv;
    if ((t & 63) == 0) red[t >> 6] = s;
    __syncthreads();
    if (t == 0) {
      const double n = sqrt(red[0] + red[1] + red[2] + red[3]);
      const double inv = 1.0 / fmax(n, 1e-12);
      *inv_out = inv;
      sinv = inv;
    }
    __syncthreads();
    const float invn = (float)sinv;
    ushort4 o;
    o.x = f16_bits(v.x * invn); o.y = f16_bits(v.y * invn);
    o.z = f16_bits(v.z * invn); o.w = f16_bits(v.w * invn);
    reinterpret_cast<ushort4*>(dst)[t] = o;
  } else {
    // ---- prep_vt branch: 16x16 transpose tile ----
    const int tile = blk - (B_ROWS + A_ROWS);
    const int tx = t & 15, ty = t >> 4;
    __shared__ float sm[16][17];
    const int h0 = (tile & 63) * 16, a0 = (tile >> 6) * 16;
    sm[ty][tx] = values[(size_t)(a0 + ty) * H_DIM + h0 + tx];
    __syncthreads();
    vbT[(size_t)(h0 + ty) * A_ROWS + a0 + tx] = bf16_rne(sm[tx][ty]);
  }
}

// ------ 256x256 / BK=64 / 8-wave / 8-phase read-ahead GEMM core -----------
// LDS: buf0 {A:[256][64] @0, B @16384}, buf1 {A @32768, B @49152} (shorts).
// Chunk-XOR swizzle: row r's chunk k (16B) lives at slot k^(r&7); staging
// pre-swizzles the per-lane GLOBAL source so the LDS dest stays linear.
#define GBAR() do { __builtin_amdgcn_s_barrier(); \
                    asm volatile("" ::: "memory"); } while (0)
#define GVMC(n) asm volatile("s_waitcnt vmcnt(" #n ")" ::: "memory")

#define SCA(buf, c, kv) gload16(aS + (size_t)(c) * 64 * KDIM + (kv), \
                                (buf) + (c) * 4096 + tid * 8)
#define SCB(buf, c, kv) gload16(bS + (size_t)(c) * 64 * KDIM + (kv), \
                                (buf) + (c) * 4096 + tid * 8)

// frag reads: plain C++ short8 loads off precomputed swizzled bases;
// compiler inserts counted lgkmcnt and interleaves with MFMA.
#define LDX(pk0, pk1, mh) do { \
    _Pragma("unroll") for (int m_ = 0; m_ < 4; ++m_) { \
      Xf[0][m_] = *reinterpret_cast<const short8*>((pk0) + (mh) * 8192 + m_ * 1024); \
      Xf[1][m_] = *reinterpret_cast<const short8*>((pk1) + (mh) * 8192 + m_ * 1024); \
    } } while (0)

#define LDB(pk0, pk1, nh) do { \
    _Pragma("unroll") for (int n_ = 0; n_ < 2; ++n_) { \
      Bf[nh][0][n_] = *reinterpret_cast<const short8*>((pk0) + (nh) * 8192 + n_ * 1024); \
      Bf[nh][1][n_] = *reinterpret_cast<const short8*>((pk1) + (nh) * 8192 + n_ * 1024); \
    } } while (0)

#define MM4(mh, nh) do { \
    __builtin_amdgcn_s_setprio(1); \
    _Pragma("unroll") for (int ki_ = 0; ki_ < 2; ++ki_) \
    _Pragma("unroll") for (int m_ = 0; m_ < 4; ++m_) \
    _Pragma("unroll") for (int n_ = 0; n_ < 2; ++n_) \
      acc[(mh) * 4 + m_][(nh) * 2 + n_] = mm16<F16>( \
          Xf[ki_][m_], Bf[nh][ki_][n_], acc[(mh) * 4 + m_][(nh) * 2 + n_]); \
    __builtin_amdgcn_s_setprio(0); \
  } while (0)

template <int KDIM, bool F16>
__device__ __forceinline__ void gemm_core(
    const unsigned short* __restrict__ Amat, int m0,
    const unsigned short* __restrict__ Bmat, int n0,
    unsigned short* smem, f32x4 (&acc)[8][4], const int tid) {
  static_assert(KDIM % 128 == 0 && KDIM >= 256, "KDIM");
  const int lane = tid & 63, w = tid >> 6;
  const int wr = w >> 2, wc = w & 3;
  const int cl = lane & 15, kg = lane >> 4;
  unsigned short* const A0b = smem;
  unsigned short* const B0b = smem + 16384;
  unsigned short* const A1b = smem + 32768;
  unsigned short* const B1b = smem + 49152;
  // staging geometry: call c covers rows c*64 + (tid>>3), chunk slot tid&7;
  // source chunk = slot ^ (row&7); (c*64)&7==0 so the XOR is c-invariant.
  const int srow = tid >> 3;
  const int tcs = (tid & 7) ^ (srow & 7);
  const unsigned short* aS = Amat + (size_t)(m0 + srow) * KDIM + tcs * 8;
  const unsigned short* bS = Bmat + (size_t)(n0 + srow) * KDIM + tcs * 8;

  // frag-read swizzle constants: row&7 == cl&7 for all frag rows, so the
  // chunk index is lane-constant: cc = (ki*4+kg)^(cl&7); ki flips ^32 shorts.
  const int cc0 = kg ^ (cl & 7);
  const int oA0 = (wr * 64 + cl) * 64 + cc0 * 8;
  const int oA1 = oA0 ^ 32;
  const int oB0 = (wc * 32 + cl) * 64 + cc0 * 8;
  const int oB1 = oB0 ^ 32;
  const unsigned short* const pA0k0 = A0b + oA0;
  const unsigned short* const pA0k1 = A0b + oA1;
  const unsigned short* const pA1k0 = A1b + oA0;
  const unsigned short* const pA1k1 = A1b + oA1;
  const unsigned short* const pB0k0 = B0b + oB0;
  const unsigned short* const pB0k1 = B0b + oB1;
  const unsigned short* const pB1k0 = B1b + oB0;
  const unsigned short* const pB1k1 = B1b + oB1;

  short8 Xf[2][4], Bf[2][2][2];

  // prologue: t0 full (8) + t1 sans A-h1 (6) = 14 loads; wait all but t1's 6
  SCA(A0b, 0, 0); SCA(A0b, 1, 0);
  SCB(B0b, 0, 0); SCB(B0b, 1, 0);
  SCB(B0b, 2, 0); SCB(B0b, 3, 0);
  SCA(A0b, 2, 0); SCA(A0b, 3, 0);
  SCA(A1b, 0, 64); SCA(A1b, 1, 64);
  SCB(B1b, 0, 64); SCB(B1b, 1, 64);
  SCB(B1b, 2, 64); SCB(B1b, 3, 64);
  GVMC(6);
  GBAR();
  LDX(pA0k0, pA0k1, 0);  // X0(t0)
  LDB(pB0k0, pB0k1, 0);  // B0(t0)

  constexpr int G = KDIM / 128;  // groups of 2 K-tiles
#pragma unroll 1
  for (int g = 0; g < G - 1; ++g) {
    const int kA = g * 128 + 64;   // t1 = 2g+1 (buf1): A-h1 staged ph1
    const int kB = g * 128 + 128;  // t2 = 2g+2 (buf0): staged ph2-5
    const int kC = g * 128 + 192;  // t3 = 2g+3 (buf1): 3 halves, ph6-8
    // ph1: MM(0,0)=X0*B0; read B1 (for ph2)
    SCA(A1b, 2, kA); SCA(A1b, 3, kA);
    LDB(pB0k0, pB0k1, 1);
    MM4(0, 0);
    GBAR();
    // ph2: MM(0,1)=X0*B1; post-MM read X1 (SSA: MM reads old Xf)
    SCA(A0b, 0, kB); SCA(A0b, 1, kB);
    MM4(0, 1);
    LDX(pA0k0, pA0k1, 1);
    GBAR();
    // ph3: MM(1,0)=X1*B0
    SCB(B0b, 0, kB); SCB(B0b, 1, kB);
    MM4(1, 0);
    GBAR();
    // ph4: MM(1,1)=X1*B1 first; then vmc6+BAR (t1 resident all-waves);
    // then read X0',B0' (drain under ph5's MM issue).
    SCB(B0b, 2, kB); SCB(B0b, 3, kB);
    MM4(1, 1);
    GVMC(6);
    GBAR();
    LDX(pA1k0, pA1k1, 0);
    LDB(pB1k0, pB1k1, 0);
    GBAR();
    // ph5: MM(0,0)'=X0'*B0'; read B1'
    SCA(A0b, 2, kB); SCA(A0b, 3, kB);
    LDB(pB1k0, pB1k1, 1);
    MM4(0, 0);
    GBAR();
    // ph6: MM(0,1)'=X0'*B1'; post-MM read X1'
    SCA(A1b, 0, kC); SCA(A1b, 1, kC);
    MM4(0, 1);
    LDX(pA1k0, pA1k1, 1);
    GBAR();
    // ph7: MM(1,0)'=X1'*B0'
    SCB(B1b, 0, kC); SCB(B1b, 1, kC);
    MM4(1, 0);
    GBAR();
    // ph8: MM(1,1)'=X1'*B1' first; vmc6+BAR (t2 resident); read X0'',B0''
    SCB(B1b, 2, kC); SCB(B1b, 3, kC);
    MM4(1, 1);
    GVMC(6);
    GBAR();
    LDX(pA0k0, pA0k1, 0);
    LDB(pB0k0, pB0k1, 0);
    GBAR();
  }
  // tail group: t_{2G-2}(buf0), t_{2G-1}(buf1); only t_{2G-1} A-h1 to stage
  {
    const int kA = KDIM - 64;
    SCA(A1b, 2, kA); SCA(A1b, 3, kA);
    LDB(pB0k0, pB0k1, 1);
    MM4(0, 0);
    GBAR();
    MM4(0, 1);
    LDX(pA0k0, pA0k1, 1);
    GBAR();
    MM4(1, 0);
    GBAR();
    MM4(1, 1);
    GVMC(0);
    GBAR();
    LDX(pA1k0, pA1k1, 0);
    LDB(pB1k0, pB1k1, 0);
    GBAR();
    LDB(pB1k0, pB1k1, 1);
    MM4(0, 0);
    GBAR();
    MM4(0, 1);
    LDX(pA1k0, pA1k1, 1);
    GBAR();
    MM4(1, 0);
    GBAR();
    MM4(1, 1);
  }
}

// ---- GEMM1: f16 core + quantize/flag + IN-BLOCK fixup + single flush ------
__global__ __launch_bounds__(512, 2) void gemm1_k(
    const unsigned short* __restrict__ xh, const unsigned short* __restrict__ ah,
    const float* __restrict__ x, const float* __restrict__ anc,
    const double* __restrict__ inv_norms, unsigned short* __restrict__ kb2) {
  __shared__ __align__(128) unsigned short smem[65536];  // 128 KB
  __shared__ unsigned int lmeta[2048];

  const int tid = threadIdx.x, lane = tid & 63, w = tid >> 6;
  const int wr = w >> 2, wc = w & 3;
  const int cl = lane & 15, kg = lane >> 4;
  // XCD-bijective swizzle (m204; nwg=512, nwg%8==0, q=64)
  const int orig = blockIdx.y * 8 + blockIdx.x;
  const int swz = (orig & 7) * 64 + (orig >> 3);
  const int m0 = (swz >> 3) * 256, n0 = (swz & 7) * 256;

  f32x4 acc[8][4];
#pragma unroll
  for (int m = 0; m < 8; ++m)
#pragma unroll
    for (int n = 0; n < 4; ++n)
#pragma unroll
      for (int q = 0; q < 4; ++q) acc[m][n][q] = 0.0f;

  if (tid == 0) lmeta[0] = 0;  // published by core's prologue barrier

  gemm_core<D_DIM, true>(xh, m0, ah, n0, smem, acc, tid);

  // ---- epilogue A: quantize -> bf16 2k in LDS (XOR-swz) + local flags ----
  __syncthreads();
  unsigned short* sq = smem;  // [256][256] bf16, chunk-swizzled
#pragma unroll
  for (int mi = 0; mi < 8; ++mi)
#pragma unroll
    for (int ni = 0; ni < 4; ++ni) {
      const int rowb = (mi >> 2) * 128 + wr * 64 + (mi & 3) * 16 + kg * 4;
      const int col = (ni >> 1) * 128 + wc * 32 + (ni & 1) * 16 + cl;
#pragma unroll
      for (int reg = 0; reg < 4; ++reg) {
        const int row = rowb + reg;
        const float kr = acc[mi][ni][reg] * 20.0f;
        const float rr = rintf(kr);
        if (0.5f - fabsf(kr - rr) < 2e-3f) {  // r7-r30-validated window
          const unsigned int code = ((unsigned int)row << 8) | (unsigned int)col;
          const unsigned int li = atomicAdd(&lmeta[0], 1u);  // LDS atomic
          if (li < LCAP) lmeta[1 + li] = code;  // ~262 expected, 2040 cap
        }
        // swizzled store: chunk (col>>3) with low 3 bits XOR (row&7)
        const int ch = col >> 3;
        const int csw = (ch & 24) | ((ch & 7) ^ (row & 7));
        sq[row * 256 + csw * 8 + (col & 7)] =
            bf16_rne((float)(2 * (int)rr));  // exact
      }
    }
  __syncthreads();

  // ---- epilogue B: in-block fixup (waves split flag list, 2-deep pipe) ---
  {
    unsigned int cnt = lmeta[0];
    if (cnt > LCAP) cnt = LCAP;
    unsigned int i = (unsigned int)w;  // wave 0..7
    if (i < cnt) {
      unsigned int code = lmeta[1 + i];
      float4 xc0, xc1, xc2, xc3, ac0, ac1, ac2, ac3;
      {
        const int b = m0 + (int)(code >> 8), a = n0 + (int)(code & 255u);
        const float4* xp = reinterpret_cast<const float4*>(x + (size_t)b * D_DIM) + lane;
        const float4* ap = reinterpret_cast<const float4*>(anc + (size_t)a * D_DIM) + lane;
        xc0 = xp[0]; xc1 = xp[64]; xc2 = xp[128]; xc3 = xp[192];
        ac0 = ap[0]; ac1 = ap[64]; ac2 = ap[128]; ac3 = ap[192];
      }
      for (;;) {
        const unsigned int inext = i + 8;
        const bool have = inext < cnt;
        unsigned int coden = 0;
        float4 xn0, xn1, xn2, xn3, an0, an1, an2, an3;
        if (have) {  // issue next flag's gather (hides under current compute)
          coden = lmeta[1 + inext];
          const int b = m0 + (int)(coden >> 8), a = n0 + (int)(coden & 255u);
          const float4* xp = reinterpret_cast<const float4*>(x + (size_t)b * D_DIM) + lane;
          const float4* ap = reinterpret_cast<const float4*>(anc + (size_t)a * D_DIM) + lane;
          xn0 = xp[0]; xn1 = xp[64]; xn2 = xp[128]; xn3 = xp[192];
          an0 = ap[0]; an1 = ap[64]; an2 = ap[128]; an3 = ap[192];
        }
        {
          double p0 = (double)xc0.x * (double)ac0.x + (double)xc0.y * (double)ac0.y +
                      (double)xc0.z * (double)ac0.z + (double)xc0.w * (double)ac0.w;
          double p1 = (double)xc1.x * (double)ac1.x + (double)xc1.y * (double)ac1.y +
                      (double)xc1.z * (double)ac1.z + (double)xc1.w * (double)ac1.w;
          double p2 = (double)xc2.x * (double)ac2.x + (double)xc2.y * (double)ac2.y +
                      (double)xc2.z * (double)ac2.z + (double)xc2.w * (double)ac2.w;
          double p3 = (double)xc3.x * (double)ac3.x + (double)xc3.y * (double)ac3.y +
                      (double)xc3.z * (double)ac3.z + (double)xc3.w * (double)ac3.w;
          double s = (p0 + p1) + (p2 + p3);
          s += __shfl_xor(s, 32);
          s += __shfl_xor(s, 16);
          s += __shfl_xor(s, 8);
          s += __shfl_xor(s, 4);
          s += __shfl_xor(s, 2);
          s += __shfl_xor(s, 1);
          if (lane == 0) {
            const int lrow = (int)(code >> 8), lcol = (int)(code & 255u);
            const int b = m0 + lrow, a = n0 + lcol;
            const double sim = s * inv_norms[b] * inv_norms[B_ROWS + a];
            const double kr = sim / 0.05;
            const double r = rint(kr);
            const double fr = kr - r;
            int k2 = 2 * (int)r;
            if (0.5 - fabs(fr) < 2.5e-6) k2 += (fr > 0.0) ? 1 : -1;  // hedge
            const int ch = lcol >> 3;
            const int csw = (ch & 24) | ((ch & 7) ^ (lrow & 7));
            sq[lrow * 256 + csw * 8 + (lcol & 7)] = bf16_rne((float)k2);
          }
        }
        if (!have) break;
        i = inext; code = coden;
        xc0 = xn0; xc1 = xn1; xc2 = xn2; xc3 = xn3;
        ac0 = an0; ac1 = an1; ac2 = an2; ac3 = an3;
      }
    }
  }
  __syncthreads();

  // ---- epilogue C: single coalesced flush sq -> kb2 ----------------------
  {
    const int row = tid >> 1, half = tid & 1;
    unsigned short* dst = kb2 + (size_t)(m0 + row) * A_ROWS + n0 + half * 128;
#pragma unroll
    for (int j = 0; j < 16; ++j) {
      const int creal = half * 16 + j;
      const int csw = (creal & 24) | ((creal & 7) ^ (row & 7));
      reinterpret_cast<int4*>(dst)[j] =
          *reinterpret_cast<const int4*>(sq + row * 256 + csw * 8);
    }
  }
}

// ---- GEMM2: bf16 chain, K=2048, 256^2 8-phase core, out = .025*k2@vbT -----
__global__ __launch_bounds__(512, 2) void gemm2_k(
    const unsigned short* __restrict__ kb2, const unsigned short* __restrict__ vbT,
    float* __restrict__ out) {
  __shared__ __align__(128) unsigned short smem[65536];  // 128 KB

  const int tid = threadIdx.x, lane = tid & 63, w = tid >> 6;
  const int wr = w >> 2, wc = w & 3;
  const int cl = lane & 15, kg = lane >> 4;
  // XCD-bijective swizzle (nwg=256, q=32)
  const int orig = blockIdx.y * 4 + blockIdx.x;
  const int swz = (orig & 7) * 32 + (orig >> 3);
  const int m0 = (swz >> 2) * 256, h0 = (swz & 3) * 256;

  f32x4 acc[8][4];
#pragma unroll
  for (int m = 0; m < 8; ++m)
#pragma unroll
    for (int n = 0; n < 4; ++n)
#pragma unroll
      for (int q = 0; q < 4; ++q) acc[m][n][q] = 0.0f;

  gemm_core<A_ROWS, false>(kb2, m0, vbT, h0, smem, acc, tid);

#pragma unroll
  for (int mi = 0; mi < 8; ++mi)
#pragma unroll
    for (int ni = 0; ni < 4; ++ni) {
      const int rowb = (mi >> 2) * 128 + wr * 64 + (mi & 3) * 16 + kg * 4;
      const int col = (ni >> 1) * 128 + wc * 32 + (ni & 1) * 16 + cl;
#pragma unroll
      for (int reg = 0; reg < 4; ++reg)
        out[(size_t)(m0 + rowb + reg) * H_DIM + h0 + col] =
            0.025f * acc[mi][ni][reg];
    }
}

// ---------------------------------------------------------------------------
extern "C" void kernel_launch(void* const* d_in, const int* in_sizes, int n_in,
                              void* d_out, int out_size, void* d_ws, size_t ws_size,
                              hipStream_t stream) {
  const float* x      = (const float*)d_in[0];
  const float* anc    = (const float*)d_in[1];
  const float* values = (const float*)d_in[2];
  float* out = (float*)d_out;

  char* ws = (char*)d_ws;
  double* inv_norms    = (double*)(ws);
  unsigned short* xh   = (unsigned short*)(ws + 0x324000);
  unsigned short* ah   = (unsigned short*)(ws + 0x2324000);
  unsigned short* vbT  = (unsigned short*)(ws + 0x2724000);
  unsigned short* kb2  = (unsigned short*)(ws + 0x2B24000);

  prep_k<<<B_ROWS + A_ROWS + (H_DIM / 16) * (A_ROWS / 16), 256, 0, stream>>>(
      x, anc, values, inv_norms, xh, ah, vbT);
  gemm1_k<<<dim3(A_ROWS / 256, B_ROWS / 256), 512, 0, stream>>>(
      xh, ah, x, anc, inv_norms, kb2);
  gemm2_k<<<dim3(H_DIM / 256, B_ROWS / 256), 512, 0, stream>>>(kb2, vbT, out);
}